// Round 7
// baseline (1170.552 us; speedup 1.0000x reference)
//
#include <hip/hip_runtime.h>
#include <hip/hip_cooperative_groups.h>
#include <cstdint>
#include <cstddef>

namespace cg = cooperative_groups;

// ---------------------------------------------------------------------------
// Net_25950192402497: 2-layer MLP-message GNN + link-prediction head.
// Identity: segment_sum(concat(x_i,x_j,ef)@W + b) over dst
//   = deg*(h@Wi + b) + (gather-sum h[src])@Wj + (gather-sum ef)@We
// R7: ONE persistent cooperative kernel, grid.sync() between phases.
// R6 was 18 small kernels, each <40us; launch gaps + tails dominated.
// nf fp32->bf16 convert fused into conv1 staging (F_IN32).
// ---------------------------------------------------------------------------

typedef __attribute__((ext_vector_type(8))) short short8;
typedef __attribute__((ext_vector_type(4))) float float4v;

__device__ __forceinline__ ushort f2b(float f) {
    uint u = __float_as_uint(f);
    u = u + 0x7fff + ((u >> 16) & 1);          // round-to-nearest-even
    return (ushort)(u >> 16);
}
__device__ __forceinline__ float b2f(ushort h) {
    return __uint_as_float(((uint)h) << 16);
}
__device__ __forceinline__ uint pack2(float a, float b) {
    return (uint)f2b(a) | ((uint)f2b(b) << 16);
}

#define F_MSG     1   // X = [deg*A | B | EF | 0] in k-space (Kp=320)
#define F_RELU    2
#define F_DEGBIAS 4
#define F_OUTF    8
#define F_OUTB    16
#define F_IN32    32  // A is fp32, convert during staging

#define XS_STRIDE 72  // 144 B rows: 2-way max bank aliasing (free), 16B aligned

struct MegaParams {
    const float* nf; const int* ei; const float* ef; const int* eli;
    const float* c1pW; const float* c1pb; const float* c1mW; const float* c1mb;
    const float* c2pW; const float* c2pb; const float* c2mW; const float* c2mb;
    const float* lpW; const float* lpb;
    float* out;
    float* x2f; float* DEG;
    int* counts; int* rowstart; int* cursor; int* blocksums;
    ushort* h_bf; ushort* agg_bf; ushort* x1_bf; ushort* ef_bf;
    ushort* wtp1; ushort* wtm1; ushort* wtp2; ushort* wtm2;
    int2* elist;
    int N, E, Q;
};

// 64-row x 128-col MFMA GEMM tile (verified in R6). Wt bf16 [n=128][Kp].
__device__ __forceinline__ void gemm_tile(
    int row0, const ushort* __restrict__ A, const ushort* __restrict__ B,
    const ushort* __restrict__ EF, const float* __restrict__ A32,
    const float* __restrict__ DEG, const ushort* __restrict__ Wt,
    const float* __restrict__ bias, float* __restrict__ outF,
    ushort* __restrict__ outB, int M, int Kp, int flags,
    ushort* xs, ushort* ws, int tid)
{
    const int lane = tid & 63;
    const int wave = tid >> 6;

    float4v acc[8];
#pragma unroll
    for (int t = 0; t < 8; ++t) acc[t] = (float4v){0.f, 0.f, 0.f, 0.f};

    const int arow = (wave << 4) + (lane & 15);
    const int koff = (lane >> 4) << 3;
    const int bcol = lane & 15;

    for (int kt = 0; kt < Kp; kt += 64) {
        __syncthreads();
        for (int idx = tid; idx < 128 * 8; idx += 256) {
            const int n = idx >> 3;
            const int g = idx & 7;
            const uint4 v = *(const uint4*)&Wt[(size_t)n * Kp + kt + (g << 3)];
            *(uint4*)&ws[n * XS_STRIDE + (g << 3)] = v;
        }
        if (flags & F_MSG) {
            for (int idx = tid; idx < 64 * 8; idx += 256) {
                const int r  = idx >> 3;
                const int g  = idx & 7;
                const int gr = row0 + r;
                const int kk = kt + (g << 3);
                uint4 v = make_uint4(0, 0, 0, 0);
                if (gr < M) {
                    if (kk < 128) {                       // deg * A
                        uint4 a = *(const uint4*)&A[((size_t)gr << 7) + kk];
                        const float d = DEG[gr];
                        uint* p = (uint*)&a;
#pragma unroll
                        for (int q = 0; q < 4; ++q)
                            p[q] = pack2(b2f((ushort)(p[q] & 0xffff)) * d,
                                         b2f((ushort)(p[q] >> 16)) * d);
                        v = a;
                    } else if (kk < 256) {                // B
                        v = *(const uint4*)&B[((size_t)gr << 7) + kk - 128];
                    } else if (kk < 272) {                // EF
                        v = *(const uint4*)&EF[((size_t)gr << 4) + kk - 256];
                    }
                }
                *(uint4*)&xs[r * XS_STRIDE + (g << 3)] = v;
            }
        } else if (flags & F_IN32) {
            for (int idx = tid; idx < 64 * 8; idx += 256) {
                const int r  = idx >> 3;
                const int g  = idx & 7;
                const int gr = row0 + r;
                uint4 v = make_uint4(0, 0, 0, 0);
                if (gr < M) {
                    const float4 f0 = *(const float4*)&A32[((size_t)gr << 7) + kt + (g << 3)];
                    const float4 f1 = *(const float4*)&A32[((size_t)gr << 7) + kt + (g << 3) + 4];
                    v.x = pack2(f0.x, f0.y); v.y = pack2(f0.z, f0.w);
                    v.z = pack2(f1.x, f1.y); v.w = pack2(f1.z, f1.w);
                }
                *(uint4*)&xs[r * XS_STRIDE + (g << 3)] = v;
            }
        } else {
            for (int idx = tid; idx < 64 * 8; idx += 256) {
                const int r  = idx >> 3;
                const int g  = idx & 7;
                const int gr = row0 + r;
                uint4 v = make_uint4(0, 0, 0, 0);
                if (gr < M) v = *(const uint4*)&A[((size_t)gr << 7) + kt + (g << 3)];
                *(uint4*)&xs[r * XS_STRIDE + (g << 3)] = v;
            }
        }
        __syncthreads();
#pragma unroll
        for (int s = 0; s < 64; s += 32) {
            const short8 af = *(const short8*)&xs[arow * XS_STRIDE + s + koff];
#pragma unroll
            for (int t = 0; t < 8; ++t) {
                const short8 bf = *(const short8*)&ws[((t << 4) + bcol) * XS_STRIDE + s + koff];
                acc[t] = __builtin_amdgcn_mfma_f32_16x16x32_bf16(af, bf, acc[t], 0, 0, 0);
            }
        }
    }

    const int rbase = row0 + (wave << 4) + ((lane >> 4) << 2);
#pragma unroll
    for (int t = 0; t < 8; ++t) {
        const int col = (t << 4) + bcol;
        const float bc = bias[col];
#pragma unroll
        for (int r = 0; r < 4; ++r) {
            const int row = rbase + r;
            if (row >= M) continue;
            float v = acc[t][r];
            v += (flags & F_DEGBIAS) ? DEG[row] * bc : bc;
            if (flags & F_RELU) v = fmaxf(v, 0.f);
            if (flags & F_OUTF) outF[((size_t)row << 7) + col] = v;
            if (flags & F_OUTB) outB[((size_t)row << 7) + col] = f2b(v);
        }
    }
}

__device__ __forceinline__ void gather_h_phase(
    const int2* __restrict__ elist, const int* __restrict__ rowstart,
    const ushort* __restrict__ h, ushort* __restrict__ agg,
    int N, int G, int tid)
{
    const int nvb = (N + 3) / 4;
    const int lane = tid & 63;
    const int wave = tid >> 6;
    for (int vb = blockIdx.x; vb < nvb; vb += G) {
        const int node = vb * 4 + wave;
        if (node >= N) continue;
        const int beg = rowstart[node];
        const int end = rowstart[node + 1];
        float ax = 0.f, ay = 0.f;
        int k = beg;
        for (; k + 1 < end; k += 2) {
            const int s0 = elist[k].x;
            const int s1 = elist[k + 1].x;
            const uint v0 = *(const uint*)&h[((size_t)s0 << 7) + (lane << 1)];
            const uint v1 = *(const uint*)&h[((size_t)s1 << 7) + (lane << 1)];
            ax += b2f((ushort)(v0 & 0xffff)) + b2f((ushort)(v1 & 0xffff));
            ay += b2f((ushort)(v0 >> 16))    + b2f((ushort)(v1 >> 16));
        }
        if (k < end) {
            const uint v = *(const uint*)&h[((size_t)elist[k].x << 7) + (lane << 1)];
            ax += b2f((ushort)(v & 0xffff));
            ay += b2f((ushort)(v >> 16));
        }
        *(uint*)&agg[((size_t)node << 7) + (lane << 1)] = pack2(ax, ay);
    }
}

__global__ __launch_bounds__(256, 4) void mega(MegaParams p)
{
    __shared__ ushort smem[64 * XS_STRIDE + 128 * XS_STRIDE];  // 27.6 KB
    ushort* xs = smem;
    ushort* ws = smem + 64 * XS_STRIDE;
    int* sint = (int*)smem;

    cg::grid_group grid = cg::this_grid();
    const int tid  = threadIdx.x;
    const int G    = gridDim.x;
    const int gtid = blockIdx.x * 256 + tid;
    const int gstr = G * 256;
    const int N = p.N, E = p.E, Q = p.Q;
    const int gemmTiles = (N + 63) / 64;
    const int nch = (N + 255) / 256;

    // ---- P0: zero counts + convert weights (bf16, transposed, padded) ----
    for (int i = gtid; i < N; i += gstr) p.counts[i] = 0;
    for (int idx = gtid; idx < 128 * 128; idx += gstr) {
        const int n = idx >> 7, k = idx & 127;
        p.wtp1[idx] = f2b(p.c1pW[(size_t)k * 128 + n]);
        p.wtp2[idx] = f2b(p.c2pW[(size_t)k * 128 + n]);
    }
    for (int idx = gtid; idx < 128 * 320; idx += gstr) {
        const int n = idx / 320, k = idx - n * 320;
        const ushort v1 = (k < 272) ? f2b(p.c1mW[(size_t)k * 128 + n]) : (ushort)0;
        const ushort v2 = (k < 272) ? f2b(p.c2mW[(size_t)k * 128 + n]) : (ushort)0;
        p.wtm1[idx] = v1;
        p.wtm2[idx] = v2;
    }
    grid.sync();

    // ---- P1: degree histogram ----
    for (int e = gtid; e < E; e += gstr) atomicAdd(&p.counts[p.ei[E + e]], 1);
    grid.sync();

    // ---- P2: per-chunk exclusive scan + chunk totals ----
    for (int vb = blockIdx.x; vb < nch; vb += G) {
        const int i = vb * 256 + tid;
        const int v = (i < N) ? p.counts[i] : 0;
        sint[tid] = v;
        __syncthreads();
        for (int off = 1; off < 256; off <<= 1) {
            const int add = (tid >= off) ? sint[tid - off] : 0;
            __syncthreads();
            sint[tid] += add;
            __syncthreads();
        }
        if (i < N) p.rowstart[i] = sint[tid] - v;
        if (tid == 255) p.blocksums[vb] = sint[255];
        __syncthreads();
    }
    grid.sync();

    // ---- P3: add chunk offsets; emit cursor + float degree ----
    for (int vb = blockIdx.x; vb < nch; vb += G) {
        int part = 0;
        for (int j = tid; j < vb; j += 256) part += p.blocksums[j];
        sint[tid] = part;
        __syncthreads();
        for (int s = 128; s > 0; s >>= 1) {
            if (tid < s) sint[tid] += sint[tid + s];
            __syncthreads();
        }
        const int off = sint[0];
        __syncthreads();
        const int i = vb * 256 + tid;
        if (i < N) {
            const int rs = p.rowstart[i] + off;
            p.rowstart[i] = rs;
            p.cursor[i]   = rs;
            p.DEG[i]      = (float)p.counts[i];
        }
    }
    if (blockIdx.x == 0 && tid == 0) p.rowstart[N] = E;
    grid.sync();

    // ---- P4: build edge list (CSR) + conv1 pre-GEMM (fp32 nf -> bf16 h1) ----
    for (int vb = blockIdx.x; vb < gemmTiles; vb += G)
        gemm_tile(vb << 6, nullptr, nullptr, nullptr, p.nf, p.DEG, p.wtp1, p.c1pb,
                  nullptr, p.h_bf, N, 128, F_RELU | F_OUTB | F_IN32, xs, ws, tid);
    for (int e = gtid; e < E; e += gstr) {
        const int d = p.ei[E + e];
        const int pos = atomicAdd(&p.cursor[d], 1);
        p.elist[pos] = make_int2(p.ei[e], e);
    }
    grid.sync();

    // ---- P5: gather_ef + gather h1 ----
    {
        const int nvb = (N + 15) / 16;
        const int lane16 = tid & 15;
        for (int vb = blockIdx.x; vb < nvb; vb += G) {
            const int node = vb * 16 + (tid >> 4);
            if (node >= N) continue;
            const int beg = p.rowstart[node];
            const int end = p.rowstart[node + 1];
            float acc = 0.f;
            for (int k = beg; k < end; ++k)
                acc += p.ef[((size_t)p.elist[k].y << 4) + lane16];
            p.ef_bf[((size_t)node << 4) + lane16] = f2b(acc);
        }
    }
    gather_h_phase(p.elist, p.rowstart, p.h_bf, p.agg_bf, N, G, tid);
    grid.sync();

    // ---- P6: conv1 message GEMM -> x1 (bf16, relu) ----
    for (int vb = blockIdx.x; vb < gemmTiles; vb += G)
        gemm_tile(vb << 6, p.h_bf, p.agg_bf, p.ef_bf, nullptr, p.DEG, p.wtm1, p.c1mb,
                  nullptr, p.x1_bf, N, 320, F_MSG | F_RELU | F_DEGBIAS | F_OUTB,
                  xs, ws, tid);
    grid.sync();

    // ---- P7: conv2 pre-GEMM -> h2 ----
    for (int vb = blockIdx.x; vb < gemmTiles; vb += G)
        gemm_tile(vb << 6, p.x1_bf, nullptr, nullptr, nullptr, p.DEG, p.wtp2, p.c2pb,
                  nullptr, p.h_bf, N, 128, F_RELU | F_OUTB, xs, ws, tid);
    grid.sync();

    // ---- P8: gather h2 ----
    gather_h_phase(p.elist, p.rowstart, p.h_bf, p.agg_bf, N, G, tid);
    grid.sync();

    // ---- P9: conv2 message GEMM -> x2 (fp32, no relu) ----
    for (int vb = blockIdx.x; vb < gemmTiles; vb += G)
        gemm_tile(vb << 6, p.h_bf, p.agg_bf, p.ef_bf, nullptr, p.DEG, p.wtm2, p.c2mb,
                  p.x2f, nullptr, N, 320, F_MSG | F_DEGBIAS | F_OUTF, xs, ws, tid);
    grid.sync();

    // ---- P10: link-prediction head (one wave per query) ----
    {
        const long long total = (long long)Q << 6;
        for (long long gt = (long long)gtid; gt < total; gt += (long long)gstr) {
            const int q = (int)(gt >> 6);
            const int lane = tid & 63;
            const int a = p.eli[q];
            const int b = p.eli[Q + q];
            const float* rowp = (lane < 32)
                ? p.x2f + ((size_t)a << 7) + (lane << 2)
                : p.x2f + ((size_t)b << 7) + ((lane - 32) << 2);
            const float4 v = *(const float4*)rowp;
            const int k0 = lane << 2;
            const float4 wA = *(const float4*)(p.lpW + (k0 << 1));
            const float4 wB = *(const float4*)(p.lpW + (k0 << 1) + 4);
            float c0 = v.x * wA.x + v.y * wA.z + v.z * wB.x + v.w * wB.z;
            float c1 = v.x * wA.y + v.y * wA.w + v.z * wB.y + v.w * wB.w;
#pragma unroll
            for (int off = 32; off > 0; off >>= 1) {
                c0 += __shfl_down(c0, off);
                c1 += __shfl_down(c1, off);
            }
            if (lane == 0) {
                p.out[(size_t)q * 2 + 0] = c0 + p.lpb[0];
                p.out[(size_t)q * 2 + 1] = c1 + p.lpb[1];
            }
        }
    }
}

extern "C" void kernel_launch(void* const* d_in, const int* in_sizes, int n_in,
                              void* d_out, int out_size, void* d_ws, size_t ws_size,
                              hipStream_t stream)
{
    MegaParams p;
    p.nf   = (const float*)d_in[0];
    p.ei   = (const int*)d_in[1];
    p.ef   = (const float*)d_in[2];
    p.eli  = (const int*)d_in[3];
    p.c1pW = (const float*)d_in[4];
    p.c1pb = (const float*)d_in[5];
    p.c1mW = (const float*)d_in[6];
    p.c1mb = (const float*)d_in[7];
    p.c2pW = (const float*)d_in[8];
    p.c2pb = (const float*)d_in[9];
    p.c2mW = (const float*)d_in[10];
    p.c2mb = (const float*)d_in[11];
    p.lpW  = (const float*)d_in[12];
    p.lpb  = (const float*)d_in[13];
    p.out  = (float*)d_out;

    const int N = in_sizes[0] / 128;
    const int E = in_sizes[1] / 2;
    const int Q = in_sizes[3] / 2;
    p.N = N; p.E = E; p.Q = Q;

    // ---- workspace layout ----
    float* x2f = (float*)d_ws;                 // N*128 fp32
    float* DEG = x2f + (size_t)N * 128;        // N
    int* counts    = (int*)(DEG + N);          // N
    int* rowstart  = counts + N;               // N+1
    int* cursor    = rowstart + N + 1;         // N
    int* blocksums = cursor + N;               // 1024 pad
    uintptr_t up = (uintptr_t)(blocksums + 1024);
    up = (up + 15) & ~(uintptr_t)15;
    ushort* h_bf   = (ushort*)up;              // N*128
    ushort* agg_bf = h_bf   + (size_t)N * 128; // N*128
    ushort* x1_bf  = agg_bf + (size_t)N * 128; // N*128
    ushort* ef_bf  = x1_bf  + (size_t)N * 128; // N*16
    ushort* wtp1   = ef_bf  + (size_t)N * 16;  // 128*128
    ushort* wtm1   = wtp1 + 128 * 128;         // 128*320
    ushort* wtp2   = wtm1 + 128 * 320;         // 128*128
    ushort* wtm2   = wtp2 + 128 * 128;         // 128*320
    uintptr_t ep = (uintptr_t)(wtm2 + 128 * 320);
    ep = (ep + 7) & ~(uintptr_t)7;
    p.x2f = x2f; p.DEG = DEG;
    p.counts = counts; p.rowstart = rowstart; p.cursor = cursor; p.blocksums = blocksums;
    p.h_bf = h_bf; p.agg_bf = agg_bf; p.x1_bf = x1_bf; p.ef_bf = ef_bf;
    p.wtp1 = wtp1; p.wtm1 = wtm1; p.wtp2 = wtp2; p.wtm2 = wtm2;
    p.elist = (int2*)ep;                       // E int2

    // grid = exact co-residency capacity (cooperative launch requires it)
    int blocksPerCU = 0;
    hipOccupancyMaxActiveBlocksPerMultiprocessor(&blocksPerCU, mega, 256, 0);
    if (blocksPerCU < 1) blocksPerCU = 1;
    hipDeviceProp_t prop;
    int dev = 0;
    hipGetDevice(&dev);
    hipGetDeviceProperties(&prop, dev);
    int grid = blocksPerCU * prop.multiProcessorCount;
    if (grid > 2048) grid = 2048;

    void* args[] = { &p };
    hipLaunchCooperativeKernel((void*)mega, dim3(grid), dim3(256), args, 0, stream);
}

// Round 8
// 378.549 us; speedup vs baseline: 3.0922x; 3.0922x over previous
//
#include <hip/hip_runtime.h>
#include <cstdint>
#include <cstddef>

// ---------------------------------------------------------------------------
// Net_25950192402497: 2-layer MLP-message GNN + link-prediction head.
// Identity: segment_sum(concat(x_i,x_j,ef)@W + b) over dst
//   = deg*(h@Wi + b) + (gather-sum h[src])@Wj + (gather-sum ef)@We
// R8: back to multi-kernel (R7 coop mega-kernel cost ~130us PER grid.sync
// on 8 XCDs -> 3x regression). vs R6: 128-row GEMM tiles (half the weight
// restaging), launches fused 18->12, nf convert fused into conv1 staging,
// x2 stored bf16 (halves head gather traffic).
// ---------------------------------------------------------------------------

typedef __attribute__((ext_vector_type(8))) short short8;
typedef __attribute__((ext_vector_type(4))) float float4v;

__device__ __forceinline__ ushort f2b(float f) {
    uint u = __float_as_uint(f);
    u = u + 0x7fff + ((u >> 16) & 1);          // round-to-nearest-even
    return (ushort)(u >> 16);
}
__device__ __forceinline__ float b2f(ushort h) {
    return __uint_as_float(((uint)h) << 16);
}
__device__ __forceinline__ uint pack2(float a, float b) {
    return (uint)f2b(a) | ((uint)f2b(b) << 16);
}

#define F_MSG     1   // X = [deg*A | B | EF | 0] in k-space (Kp=320)
#define F_RELU    2
#define F_DEGBIAS 4
#define F_OUTB    8   // write bf16 output (else fp32 via outF)
#define F_IN32    16  // A is fp32, convert during staging

#define XS_STRIDE 72  // 144 B rows: max 2-way bank aliasing (free), 16B aligned

// MFMA GEMM: OUT[r,0:128] = act( X[r,0:Kp] @ W[Kp,128] + bias ).
// Wt bf16 transposed [n=128][Kp], zero-padded; Kp % 64 == 0.
// Block: 128 rows x 128 cols, 4 waves; wave w owns rows w*32..w*32+31
// (2 m-subtiles of 16), all 128 cols as 8 col-tiles. acc = 2x8 float4.
__launch_bounds__(256, 4)
__global__ void gemm_mfma(const ushort* __restrict__ A, const ushort* __restrict__ B,
                          const ushort* __restrict__ EF, const float* __restrict__ A32,
                          const float* __restrict__ DEG, const ushort* __restrict__ Wt,
                          const float* __restrict__ bias, float* __restrict__ outF,
                          ushort* __restrict__ outB, int M, int Kp, int flags)
{
    __shared__ ushort xs[128 * XS_STRIDE];   // 18 KB
    __shared__ ushort ws[128 * XS_STRIDE];   // 18 KB
    const int tid  = threadIdx.x;
    const int lane = tid & 63;
    const int wave = tid >> 6;
    const int row0 = blockIdx.x << 7;

    float4v acc[2][8];
#pragma unroll
    for (int m = 0; m < 2; ++m)
#pragma unroll
        for (int t = 0; t < 8; ++t) acc[m][t] = (float4v){0.f, 0.f, 0.f, 0.f};

    const int arow0 = (wave << 5) + (lane & 15);   // m-subtile 0 row
    const int koff  = (lane >> 4) << 3;
    const int bcol  = lane & 15;

    for (int kt = 0; kt < Kp; kt += 64) {
        __syncthreads();
        // stage ws[n][0..63] <- Wt[n][kt..kt+64)
        for (int idx = tid; idx < 128 * 8; idx += 256) {
            const int n = idx >> 3;
            const int g = idx & 7;
            const uint4 v = *(const uint4*)&Wt[(size_t)n * Kp + kt + (g << 3)];
            *(uint4*)&ws[n * XS_STRIDE + (g << 3)] = v;
        }
        // stage xs[r][0..63]
        if (flags & F_MSG) {
            for (int idx = tid; idx < 128 * 8; idx += 256) {
                const int r  = idx >> 3;
                const int g  = idx & 7;
                const int gr = row0 + r;
                const int kk = kt + (g << 3);
                uint4 v = make_uint4(0, 0, 0, 0);
                if (gr < M) {
                    if (kk < 128) {                       // deg * A
                        uint4 a = *(const uint4*)&A[((size_t)gr << 7) + kk];
                        const float d = DEG[gr];
                        uint* p = (uint*)&a;
#pragma unroll
                        for (int q = 0; q < 4; ++q)
                            p[q] = pack2(b2f((ushort)(p[q] & 0xffff)) * d,
                                         b2f((ushort)(p[q] >> 16)) * d);
                        v = a;
                    } else if (kk < 256) {                // B
                        v = *(const uint4*)&B[((size_t)gr << 7) + kk - 128];
                    } else if (kk < 272) {                // EF
                        v = *(const uint4*)&EF[((size_t)gr << 4) + kk - 256];
                    }
                }
                *(uint4*)&xs[r * XS_STRIDE + (g << 3)] = v;
            }
        } else if (flags & F_IN32) {
            for (int idx = tid; idx < 128 * 8; idx += 256) {
                const int r  = idx >> 3;
                const int g  = idx & 7;
                const int gr = row0 + r;
                uint4 v = make_uint4(0, 0, 0, 0);
                if (gr < M) {
                    const float4 f0 = *(const float4*)&A32[((size_t)gr << 7) + kt + (g << 3)];
                    const float4 f1 = *(const float4*)&A32[((size_t)gr << 7) + kt + (g << 3) + 4];
                    v.x = pack2(f0.x, f0.y); v.y = pack2(f0.z, f0.w);
                    v.z = pack2(f1.x, f1.y); v.w = pack2(f1.z, f1.w);
                }
                *(uint4*)&xs[r * XS_STRIDE + (g << 3)] = v;
            }
        } else {
            for (int idx = tid; idx < 128 * 8; idx += 256) {
                const int r  = idx >> 3;
                const int g  = idx & 7;
                const int gr = row0 + r;
                uint4 v = make_uint4(0, 0, 0, 0);
                if (gr < M) v = *(const uint4*)&A[((size_t)gr << 7) + kt + (g << 3)];
                *(uint4*)&xs[r * XS_STRIDE + (g << 3)] = v;
            }
        }
        __syncthreads();
#pragma unroll
        for (int s = 0; s < 64; s += 32) {
            const short8 a0 = *(const short8*)&xs[arow0 * XS_STRIDE + s + koff];
            const short8 a1 = *(const short8*)&xs[(arow0 + 16) * XS_STRIDE + s + koff];
#pragma unroll
            for (int t = 0; t < 8; ++t) {
                const short8 bf = *(const short8*)&ws[((t << 4) + bcol) * XS_STRIDE + s + koff];
                acc[0][t] = __builtin_amdgcn_mfma_f32_16x16x32_bf16(a0, bf, acc[0][t], 0, 0, 0);
                acc[1][t] = __builtin_amdgcn_mfma_f32_16x16x32_bf16(a1, bf, acc[1][t], 0, 0, 0);
            }
        }
    }

    // epilogue: C/D layout col=lane&15, row=(lane>>4)*4+reg
#pragma unroll
    for (int m = 0; m < 2; ++m) {
        const int rbase = row0 + (wave << 5) + (m << 4) + ((lane >> 4) << 2);
#pragma unroll
        for (int t = 0; t < 8; ++t) {
            const int col = (t << 4) + bcol;
            const float bc = bias[col];
#pragma unroll
            for (int r = 0; r < 4; ++r) {
                const int row = rbase + r;
                if (row >= M) continue;
                float v = acc[m][t][r];
                v += (flags & F_DEGBIAS) ? DEG[row] * bc : bc;
                if (flags & F_RELU) v = fmaxf(v, 0.f);
                if (flags & F_OUTB) outB[((size_t)row << 7) + col] = f2b(v);
                else                outF[((size_t)row << 7) + col] = v;
            }
        }
    }
}

// ---- prep: zero counts + convert all 4 weight matrices (bf16, T, padded) ----
__launch_bounds__(256)
__global__ void prep(const float* __restrict__ c1pW, const float* __restrict__ c2pW,
                     const float* __restrict__ c1mW, const float* __restrict__ c2mW,
                     ushort* __restrict__ wtp1, ushort* __restrict__ wtp2,
                     ushort* __restrict__ wtm1, ushort* __restrict__ wtm2,
                     int* __restrict__ counts, int N)
{
    const int gtid = blockIdx.x * 256 + threadIdx.x;
    const int gstr = gridDim.x * 256;
    for (int i = gtid; i < N; i += gstr) counts[i] = 0;
    for (int idx = gtid; idx < 128 * 128; idx += gstr) {
        const int n = idx >> 7, k = idx & 127;
        wtp1[idx] = f2b(c1pW[(size_t)k * 128 + n]);
        wtp2[idx] = f2b(c2pW[(size_t)k * 128 + n]);
    }
    for (int idx = gtid; idx < 128 * 320; idx += gstr) {
        const int n = idx / 320, k = idx - n * 320;
        wtm1[idx] = (k < 272) ? f2b(c1mW[(size_t)k * 128 + n]) : (ushort)0;
        wtm2[idx] = (k < 272) ? f2b(c2mW[(size_t)k * 128 + n]) : (ushort)0;
    }
}

__launch_bounds__(256)
__global__ void hist_kernel(const int* __restrict__ ei, int* __restrict__ counts, int E)
{
    const int e = blockIdx.x * 256 + threadIdx.x;
    if (e < E) atomicAdd(&counts[ei[E + e]], 1);
}

__launch_bounds__(256)
__global__ void scan_phase1(const int* __restrict__ counts, int* __restrict__ rowstart,
                            int* __restrict__ blocksums, int N)
{
    __shared__ int sdata[256];
    const int t = threadIdx.x;
    const int i = blockIdx.x * 256 + t;
    const int v = (i < N) ? counts[i] : 0;
    sdata[t] = v;
    __syncthreads();
    for (int off = 1; off < 256; off <<= 1) {
        const int add = (t >= off) ? sdata[t - off] : 0;
        __syncthreads();
        sdata[t] += add;
        __syncthreads();
    }
    if (i < N) rowstart[i] = sdata[t] - v;
    if (t == 255) blocksums[blockIdx.x] = sdata[255];
}

// merged scan phases 2+3: block vb sums blocksums[0..vb) itself (nch ~196)
__launch_bounds__(256)
__global__ void scan_phase23(const int* __restrict__ counts, const int* __restrict__ bs,
                             int* __restrict__ rowstart, int* __restrict__ cursor,
                             float* __restrict__ degf, int N, int E)
{
    __shared__ int sdata[256];
    const int t = threadIdx.x;
    const int vb = blockIdx.x;
    int part = 0;
    for (int j = t; j < vb; j += 256) part += bs[j];
    sdata[t] = part;
    __syncthreads();
    for (int s = 128; s > 0; s >>= 1) {
        if (t < s) sdata[t] += sdata[t + s];
        __syncthreads();
    }
    const int off = sdata[0];
    const int i = vb * 256 + t;
    if (i < N) {
        const int rs = rowstart[i] + off;
        rowstart[i] = rs;
        cursor[i]   = rs;
        degf[i]     = (float)counts[i];
    }
    if (vb == 0 && t == 0) rowstart[N] = E;
}

__launch_bounds__(256)
__global__ void build_elist(const int* __restrict__ ei, int* __restrict__ cursor,
                            int2* __restrict__ elist, int E)
{
    const int e = blockIdx.x * 256 + threadIdx.x;
    if (e >= E) return;
    const int d = ei[E + e];
    const int pos = atomicAdd(&cursor[d], 1);
    elist[pos] = make_int2(ei[e], e);
}

// gather: per-node sums. doEf: also produce aggregated edge features.
__launch_bounds__(256)
__global__ void gather(const int2* __restrict__ elist, const int* __restrict__ rowstart,
                       const ushort* __restrict__ h, ushort* __restrict__ agg,
                       const float* __restrict__ ef, ushort* __restrict__ aggef,
                       int N, int doEf)
{
    const int tid = threadIdx.x;
    if (doEf) {
        const int nvb = (N + 15) / 16;
        const int lane16 = tid & 15;
        for (int vb = blockIdx.x; vb < nvb; vb += gridDim.x) {
            const int node = vb * 16 + (tid >> 4);
            if (node >= N) continue;
            const int beg = rowstart[node];
            const int end = rowstart[node + 1];
            float acc = 0.f;
            for (int k = beg; k < end; ++k)
                acc += ef[((size_t)elist[k].y << 4) + lane16];
            aggef[((size_t)node << 4) + lane16] = f2b(acc);
        }
    }
    {
        const int nvb = (N + 3) / 4;
        const int lane = tid & 63;
        const int wave = tid >> 6;
        for (int vb = blockIdx.x; vb < nvb; vb += gridDim.x) {
            const int node = vb * 4 + wave;
            if (node >= N) continue;
            const int beg = rowstart[node];
            const int end = rowstart[node + 1];
            float ax = 0.f, ay = 0.f;
            int k = beg;
            for (; k + 1 < end; k += 2) {
                const int s0 = elist[k].x;
                const int s1 = elist[k + 1].x;
                const uint v0 = *(const uint*)&h[((size_t)s0 << 7) + (lane << 1)];
                const uint v1 = *(const uint*)&h[((size_t)s1 << 7) + (lane << 1)];
                ax += b2f((ushort)(v0 & 0xffff)) + b2f((ushort)(v1 & 0xffff));
                ay += b2f((ushort)(v0 >> 16))    + b2f((ushort)(v1 >> 16));
            }
            if (k < end) {
                const uint v = *(const uint*)&h[((size_t)elist[k].x << 7) + (lane << 1)];
                ax += b2f((ushort)(v & 0xffff));
                ay += b2f((ushort)(v >> 16));
            }
            *(uint*)&agg[((size_t)node << 7) + (lane << 1)] = pack2(ax, ay);
        }
    }
}

// pred[q,:2] = concat(x2[a], x2[b]) @ lpW + lpb — one wave per query, x2 bf16
__launch_bounds__(256)
__global__ void head_kernel(const ushort* __restrict__ x2, const int* __restrict__ eli,
                            const float* __restrict__ lpW, const float* __restrict__ lpb,
                            float* __restrict__ out, int Q)
{
    const long long gt = (long long)blockIdx.x * 256 + threadIdx.x;
    const int q = (int)(gt >> 6);
    if (q >= Q) return;
    const int lane = threadIdx.x & 63;
    const int a = eli[q];
    const int b = eli[Q + q];
    const ushort* rowp = (lane < 32)
        ? x2 + ((size_t)a << 7) + ((lane & 31) << 2)
        : x2 + ((size_t)b << 7) + ((lane & 31) << 2);
    const uint2 u = *(const uint2*)rowp;
    const float vx = b2f((ushort)(u.x & 0xffff));
    const float vy = b2f((ushort)(u.x >> 16));
    const float vz = b2f((ushort)(u.y & 0xffff));
    const float vw = b2f((ushort)(u.y >> 16));
    const int k0 = lane << 2;
    const float4 wA = *(const float4*)(lpW + (k0 << 1));
    const float4 wB = *(const float4*)(lpW + (k0 << 1) + 4);
    float c0 = vx * wA.x + vy * wA.z + vz * wB.x + vw * wB.z;
    float c1 = vx * wA.y + vy * wA.w + vz * wB.y + vw * wB.w;
#pragma unroll
    for (int off = 32; off > 0; off >>= 1) {
        c0 += __shfl_down(c0, off);
        c1 += __shfl_down(c1, off);
    }
    if (lane == 0) {
        out[(size_t)q * 2 + 0] = c0 + lpb[0];
        out[(size_t)q * 2 + 1] = c1 + lpb[1];
    }
}

extern "C" void kernel_launch(void* const* d_in, const int* in_sizes, int n_in,
                              void* d_out, int out_size, void* d_ws, size_t ws_size,
                              hipStream_t stream)
{
    const float* nf   = (const float*)d_in[0];
    const int*   ei   = (const int*)d_in[1];
    const float* ef   = (const float*)d_in[2];
    const int*   eli  = (const int*)d_in[3];
    const float* c1pW = (const float*)d_in[4];
    const float* c1pb = (const float*)d_in[5];
    const float* c1mW = (const float*)d_in[6];
    const float* c1mb = (const float*)d_in[7];
    const float* c2pW = (const float*)d_in[8];
    const float* c2pb = (const float*)d_in[9];
    const float* c2mW = (const float*)d_in[10];
    const float* c2mb = (const float*)d_in[11];
    const float* lpW  = (const float*)d_in[12];
    const float* lpb  = (const float*)d_in[13];
    float* out = (float*)d_out;

    const int N = in_sizes[0] / 128;
    const int E = in_sizes[1] / 2;
    const int Q = in_sizes[3] / 2;

    // ---- workspace layout ----
    float* DEG = (float*)d_ws;                 // N
    int* counts    = (int*)(DEG + N);          // N
    int* rowstart  = counts + N;               // N+1
    int* cursor    = rowstart + N + 1;         // N
    int* blocksums = cursor + N;               // 1024 pad
    uintptr_t up = (uintptr_t)(blocksums + 1024);
    up = (up + 15) & ~(uintptr_t)15;
    ushort* h_bf   = (ushort*)up;              // N*128
    ushort* agg_bf = h_bf   + (size_t)N * 128; // N*128
    ushort* x1_bf  = agg_bf + (size_t)N * 128; // N*128
    ushort* x2_bf  = x1_bf  + (size_t)N * 128; // N*128
    ushort* ef_bf  = x2_bf  + (size_t)N * 128; // N*16
    ushort* wtp1   = ef_bf  + (size_t)N * 16;  // 128*128
    ushort* wtm1   = wtp1 + 128 * 128;         // 128*320
    ushort* wtp2   = wtm1 + 128 * 320;         // 128*128
    ushort* wtm2   = wtp2 + 128 * 128;         // 128*320
    uintptr_t ep = (uintptr_t)(wtm2 + 128 * 320);
    ep = (ep + 7) & ~(uintptr_t)7;
    int2* elist = (int2*)ep;                   // E int2 (src, edge id)

    const int gemmGrid = (N + 127) / 128;
    const int eGrid    = (E + 255) / 256;
    const int nGrid    = (N + 255) / 256;
    const int gGrid    = (N + 3) / 4;
    const int headGrid = (int)(((long long)Q * 64 + 255) / 256);

    // ---- prep + CSR build ----
    prep<<<nGrid, 256, 0, stream>>>(c1pW, c2pW, c1mW, c2mW, wtp1, wtp2, wtm1, wtm2,
                                    counts, N);
    hist_kernel<<<eGrid, 256, 0, stream>>>(ei, counts, E);
    scan_phase1<<<nGrid, 256, 0, stream>>>(counts, rowstart, blocksums, N);
    scan_phase23<<<nGrid, 256, 0, stream>>>(counts, blocksums, rowstart, cursor, DEG, N, E);
    build_elist<<<eGrid, 256, 0, stream>>>(ei, cursor, elist, E);

    // ---- conv1 ----
    gemm_mfma<<<gemmGrid, 256, 0, stream>>>(nullptr, nullptr, nullptr, nf, DEG, wtp1,
                                            c1pb, nullptr, h_bf, N, 128,
                                            F_RELU | F_OUTB | F_IN32);
    gather<<<gGrid, 256, 0, stream>>>(elist, rowstart, h_bf, agg_bf, ef, ef_bf, N, 1);
    gemm_mfma<<<gemmGrid, 256, 0, stream>>>(h_bf, agg_bf, ef_bf, nullptr, DEG, wtm1,
                                            c1mb, nullptr, x1_bf, N, 320,
                                            F_MSG | F_RELU | F_DEGBIAS | F_OUTB);

    // ---- conv2 ----
    gemm_mfma<<<gemmGrid, 256, 0, stream>>>(x1_bf, nullptr, nullptr, nullptr, DEG, wtp2,
                                            c2pb, nullptr, h_bf, N, 128,
                                            F_RELU | F_OUTB);
    gather<<<gGrid, 256, 0, stream>>>(elist, rowstart, h_bf, agg_bf, nullptr, nullptr, N, 0);
    gemm_mfma<<<gemmGrid, 256, 0, stream>>>(h_bf, agg_bf, ef_bf, nullptr, DEG, wtm2,
                                            c2mb, nullptr, x2_bf, N, 320,
                                            F_MSG | F_DEGBIAS | F_OUTB);

    // ---- head ----
    head_kernel<<<headGrid, 256, 0, stream>>>(x2_bf, eli, lpW, lpb, out, Q);
}

// Round 9
// 331.829 us; speedup vs baseline: 3.5276x; 1.1408x over previous
//
#include <hip/hip_runtime.h>
#include <cstdint>
#include <cstddef>

// ---------------------------------------------------------------------------
// Net_25950192402497: 2-layer MLP-message GNN + link-prediction head.
// Identity: segment_sum(concat(x_i,x_j,ef)@W + b) over dst
//   = deg*(h@Wi + b) + (gather-sum h[src])@Wj + (gather-sum ef)@We
// R9 vs R8: (a) head factorized: concat(x2[a],x2[b])@lpW = za[a]+zb[b];
// za/zb (N x 2 each) computed in the conv2-msg GEMM epilogue via 16-lane
// xor-shuffle reduction — x2 never materialized, head reads 3.2MB not 51MB;
// (b) SoA edge arrays + unroll-4 gather for more memory-level parallelism.
// ---------------------------------------------------------------------------

typedef __attribute__((ext_vector_type(8))) short short8;
typedef __attribute__((ext_vector_type(4))) float float4v;

__device__ __forceinline__ ushort f2b(float f) {
    uint u = __float_as_uint(f);
    u = u + 0x7fff + ((u >> 16) & 1);          // round-to-nearest-even
    return (ushort)(u >> 16);
}
__device__ __forceinline__ float b2f(ushort h) {
    return __uint_as_float(((uint)h) << 16);
}
__device__ __forceinline__ uint pack2(float a, float b) {
    return (uint)f2b(a) | ((uint)f2b(b) << 16);
}

#define F_MSG     1   // X = [deg*A | B | EF | 0] in k-space (Kp=320)
#define F_RELU    2
#define F_DEGBIAS 4
#define F_OUTB    8   // write bf16 output
#define F_IN32    16  // A is fp32, convert during staging
#define F_HEAD    32  // no row output; emit z[row] = {za0,za1,zb0,zb1}

#define XS_STRIDE 72  // 144 B rows: max 2-way bank aliasing (free), 16B aligned

// MFMA GEMM: act( X[r,0:Kp] @ W[Kp,128] + bias ) -> bf16 rows or head-z.
// Wt bf16 transposed [n=128][Kp], zero-padded; Kp % 64 == 0.
// Block: 128 rows x 128 cols, 4 waves; wave w owns rows w*32..w*32+31
// (2 m-subtiles of 16), all 128 cols as 8 col-tiles. acc = 2x8 float4.
__launch_bounds__(256, 2)
__global__ void gemm_mfma(const ushort* __restrict__ A, const ushort* __restrict__ B,
                          const ushort* __restrict__ EF, const float* __restrict__ A32,
                          const float* __restrict__ DEG, const ushort* __restrict__ Wt,
                          const float* __restrict__ bias, ushort* __restrict__ outB,
                          const float* __restrict__ lpW, float* __restrict__ z,
                          int M, int Kp, int flags)
{
    __shared__ ushort xs[128 * XS_STRIDE];   // 18 KB
    __shared__ ushort ws[128 * XS_STRIDE];   // 18 KB
    const int tid  = threadIdx.x;
    const int lane = tid & 63;
    const int wave = tid >> 6;
    const int row0 = blockIdx.x << 7;

    float4v acc[2][8];
#pragma unroll
    for (int m = 0; m < 2; ++m)
#pragma unroll
        for (int t = 0; t < 8; ++t) acc[m][t] = (float4v){0.f, 0.f, 0.f, 0.f};

    const int arow0 = (wave << 5) + (lane & 15);
    const int koff  = (lane >> 4) << 3;
    const int bcol  = lane & 15;

    for (int kt = 0; kt < Kp; kt += 64) {
        __syncthreads();
        for (int idx = tid; idx < 128 * 8; idx += 256) {
            const int n = idx >> 3;
            const int g = idx & 7;
            const uint4 v = *(const uint4*)&Wt[(size_t)n * Kp + kt + (g << 3)];
            *(uint4*)&ws[n * XS_STRIDE + (g << 3)] = v;
        }
        if (flags & F_MSG) {
            for (int idx = tid; idx < 128 * 8; idx += 256) {
                const int r  = idx >> 3;
                const int g  = idx & 7;
                const int gr = row0 + r;
                const int kk = kt + (g << 3);
                uint4 v = make_uint4(0, 0, 0, 0);
                if (gr < M) {
                    if (kk < 128) {                       // deg * A
                        uint4 a = *(const uint4*)&A[((size_t)gr << 7) + kk];
                        const float d = DEG[gr];
                        uint* p = (uint*)&a;
#pragma unroll
                        for (int q = 0; q < 4; ++q)
                            p[q] = pack2(b2f((ushort)(p[q] & 0xffff)) * d,
                                         b2f((ushort)(p[q] >> 16)) * d);
                        v = a;
                    } else if (kk < 256) {                // B
                        v = *(const uint4*)&B[((size_t)gr << 7) + kk - 128];
                    } else if (kk < 272) {                // EF
                        v = *(const uint4*)&EF[((size_t)gr << 4) + kk - 256];
                    }
                }
                *(uint4*)&xs[r * XS_STRIDE + (g << 3)] = v;
            }
        } else if (flags & F_IN32) {
            for (int idx = tid; idx < 128 * 8; idx += 256) {
                const int r  = idx >> 3;
                const int g  = idx & 7;
                const int gr = row0 + r;
                uint4 v = make_uint4(0, 0, 0, 0);
                if (gr < M) {
                    const float4 f0 = *(const float4*)&A32[((size_t)gr << 7) + kt + (g << 3)];
                    const float4 f1 = *(const float4*)&A32[((size_t)gr << 7) + kt + (g << 3) + 4];
                    v.x = pack2(f0.x, f0.y); v.y = pack2(f0.z, f0.w);
                    v.z = pack2(f1.x, f1.y); v.w = pack2(f1.z, f1.w);
                }
                *(uint4*)&xs[r * XS_STRIDE + (g << 3)] = v;
            }
        } else {
            for (int idx = tid; idx < 128 * 8; idx += 256) {
                const int r  = idx >> 3;
                const int g  = idx & 7;
                const int gr = row0 + r;
                uint4 v = make_uint4(0, 0, 0, 0);
                if (gr < M) v = *(const uint4*)&A[((size_t)gr << 7) + kt + (g << 3)];
                *(uint4*)&xs[r * XS_STRIDE + (g << 3)] = v;
            }
        }
        __syncthreads();
#pragma unroll
        for (int s = 0; s < 64; s += 32) {
            const short8 a0 = *(const short8*)&xs[arow0 * XS_STRIDE + s + koff];
            const short8 a1 = *(const short8*)&xs[(arow0 + 16) * XS_STRIDE + s + koff];
#pragma unroll
            for (int t = 0; t < 8; ++t) {
                const short8 bf = *(const short8*)&ws[((t << 4) + bcol) * XS_STRIDE + s + koff];
                acc[0][t] = __builtin_amdgcn_mfma_f32_16x16x32_bf16(a0, bf, acc[0][t], 0, 0, 0);
                acc[1][t] = __builtin_amdgcn_mfma_f32_16x16x32_bf16(a1, bf, acc[1][t], 0, 0, 0);
            }
        }
    }

    // ---- epilogue: C/D layout col=lane&15, row=(lane>>4)*4+reg ----
    float bcv[8];
#pragma unroll
    for (int t = 0; t < 8; ++t) bcv[t] = bias[(t << 4) + bcol];

    if (flags & F_HEAD) {
        // z[row] = { row@Wtop (2), row@Wbot (2) }, W from lpW[256][2]
        const float2* lw = (const float2*)lpW;
        float2 wa[8], wb[8];
#pragma unroll
        for (int t = 0; t < 8; ++t) {
            const int col = (t << 4) + bcol;
            wa[t] = lw[col];
            wb[t] = lw[128 + col];
        }
#pragma unroll
        for (int m = 0; m < 2; ++m) {
            const int rbase = row0 + (wave << 5) + (m << 4) + ((lane >> 4) << 2);
#pragma unroll
            for (int r = 0; r < 4; ++r) {
                const int row = rbase + r;
                const float d = (row < M) ? DEG[row] : 0.f;
                float za0 = 0.f, za1 = 0.f, zb0 = 0.f, zb1 = 0.f;
#pragma unroll
                for (int t = 0; t < 8; ++t) {
                    const float v = acc[m][t][r] + d * bcv[t];
                    za0 += v * wa[t].x; za1 += v * wa[t].y;
                    zb0 += v * wb[t].x; zb1 += v * wb[t].y;
                }
#pragma unroll
                for (int mk = 8; mk > 0; mk >>= 1) {
                    za0 += __shfl_xor(za0, mk);
                    za1 += __shfl_xor(za1, mk);
                    zb0 += __shfl_xor(zb0, mk);
                    zb1 += __shfl_xor(zb1, mk);
                }
                if (bcol == 0 && row < M)
                    *(float4*)&z[(size_t)row * 4] = make_float4(za0, za1, zb0, zb1);
            }
        }
    } else {
#pragma unroll
        for (int m = 0; m < 2; ++m) {
            const int rbase = row0 + (wave << 5) + (m << 4) + ((lane >> 4) << 2);
#pragma unroll
            for (int t = 0; t < 8; ++t) {
                const int col = (t << 4) + bcol;
#pragma unroll
                for (int r = 0; r < 4; ++r) {
                    const int row = rbase + r;
                    if (row >= M) continue;
                    float v = acc[m][t][r];
                    v += (flags & F_DEGBIAS) ? DEG[row] * bcv[t] : bcv[t];
                    if (flags & F_RELU) v = fmaxf(v, 0.f);
                    outB[((size_t)row << 7) + col] = f2b(v);
                }
            }
        }
    }
}

// ---- prep: zero counts + convert all 4 weight matrices (bf16, T, padded) ----
__launch_bounds__(256)
__global__ void prep(const float* __restrict__ c1pW, const float* __restrict__ c2pW,
                     const float* __restrict__ c1mW, const float* __restrict__ c2mW,
                     ushort* __restrict__ wtp1, ushort* __restrict__ wtp2,
                     ushort* __restrict__ wtm1, ushort* __restrict__ wtm2,
                     int* __restrict__ counts, int N)
{
    const int gtid = blockIdx.x * 256 + threadIdx.x;
    const int gstr = gridDim.x * 256;
    for (int i = gtid; i < N; i += gstr) counts[i] = 0;
    for (int idx = gtid; idx < 128 * 128; idx += gstr) {
        const int n = idx >> 7, k = idx & 127;
        wtp1[idx] = f2b(c1pW[(size_t)k * 128 + n]);
        wtp2[idx] = f2b(c2pW[(size_t)k * 128 + n]);
    }
    for (int idx = gtid; idx < 128 * 320; idx += gstr) {
        const int n = idx / 320, k = idx - n * 320;
        wtm1[idx] = (k < 272) ? f2b(c1mW[(size_t)k * 128 + n]) : (ushort)0;
        wtm2[idx] = (k < 272) ? f2b(c2mW[(size_t)k * 128 + n]) : (ushort)0;
    }
}

__launch_bounds__(256)
__global__ void hist_kernel(const int* __restrict__ ei, int* __restrict__ counts, int E)
{
    const int e = blockIdx.x * 256 + threadIdx.x;
    if (e < E) atomicAdd(&counts[ei[E + e]], 1);
}

__launch_bounds__(256)
__global__ void scan_phase1(const int* __restrict__ counts, int* __restrict__ rowstart,
                            int* __restrict__ blocksums, int N)
{
    __shared__ int sdata[256];
    const int t = threadIdx.x;
    const int i = blockIdx.x * 256 + t;
    const int v = (i < N) ? counts[i] : 0;
    sdata[t] = v;
    __syncthreads();
    for (int off = 1; off < 256; off <<= 1) {
        const int add = (t >= off) ? sdata[t - off] : 0;
        __syncthreads();
        sdata[t] += add;
        __syncthreads();
    }
    if (i < N) rowstart[i] = sdata[t] - v;
    if (t == 255) blocksums[blockIdx.x] = sdata[255];
}

// merged scan phases 2+3: block vb sums blocksums[0..vb) itself (~196 blocks)
__launch_bounds__(256)
__global__ void scan_phase23(const int* __restrict__ counts, const int* __restrict__ bs,
                             int* __restrict__ rowstart, int* __restrict__ cursor,
                             float* __restrict__ degf, int N, int E)
{
    __shared__ int sdata[256];
    const int t = threadIdx.x;
    const int vb = blockIdx.x;
    int part = 0;
    for (int j = t; j < vb; j += 256) part += bs[j];
    sdata[t] = part;
    __syncthreads();
    for (int s = 128; s > 0; s >>= 1) {
        if (t < s) sdata[t] += sdata[t + s];
        __syncthreads();
    }
    const int off = sdata[0];
    const int i = vb * 256 + t;
    if (i < N) {
        const int rs = rowstart[i] + off;
        rowstart[i] = rs;
        cursor[i]   = rs;
        degf[i]     = (float)counts[i];
    }
    if (vb == 0 && t == 0) rowstart[N] = E;
}

__launch_bounds__(256)
__global__ void build_elist(const int* __restrict__ ei, int* __restrict__ cursor,
                            int* __restrict__ esrc, int* __restrict__ eeid, int E)
{
    const int e = blockIdx.x * 256 + threadIdx.x;
    if (e >= E) return;
    const int d = ei[E + e];
    const int pos = atomicAdd(&cursor[d], 1);
    esrc[pos] = ei[e];
    eeid[pos] = e;
}

// gather: per-node edge sums (SoA indices, unroll-4 for MLP)
__launch_bounds__(256)
__global__ void gather(const int* __restrict__ esrc, const int* __restrict__ eeid,
                       const int* __restrict__ rowstart,
                       const ushort* __restrict__ h, ushort* __restrict__ agg,
                       const float* __restrict__ ef, ushort* __restrict__ aggef,
                       int N, int doEf)
{
    const int tid = threadIdx.x;
    if (doEf) {
        const int nvb = (N + 15) / 16;
        const int lane16 = tid & 15;
        for (int vb = blockIdx.x; vb < nvb; vb += gridDim.x) {
            const int node = vb * 16 + (tid >> 4);
            if (node >= N) continue;
            const int beg = rowstart[node];
            const int end = rowstart[node + 1];
            float acc = 0.f;
            for (int k = beg; k < end; ++k)
                acc += ef[((size_t)eeid[k] << 4) + lane16];
            aggef[((size_t)node << 4) + lane16] = f2b(acc);
        }
    }
    {
        const int nvb = (N + 3) / 4;
        const int lane = tid & 63;
        const int wave = tid >> 6;
        for (int vb = blockIdx.x; vb < nvb; vb += gridDim.x) {
            const int node = vb * 4 + wave;
            if (node >= N) continue;
            const int beg = rowstart[node];
            const int end = rowstart[node + 1];
            float ax = 0.f, ay = 0.f;
            int k = beg;
            for (; k + 3 < end; k += 4) {
                const int s0 = esrc[k];
                const int s1 = esrc[k + 1];
                const int s2 = esrc[k + 2];
                const int s3 = esrc[k + 3];
                const uint v0 = *(const uint*)&h[((size_t)s0 << 7) + (lane << 1)];
                const uint v1 = *(const uint*)&h[((size_t)s1 << 7) + (lane << 1)];
                const uint v2 = *(const uint*)&h[((size_t)s2 << 7) + (lane << 1)];
                const uint v3 = *(const uint*)&h[((size_t)s3 << 7) + (lane << 1)];
                ax += b2f((ushort)(v0 & 0xffff)) + b2f((ushort)(v1 & 0xffff))
                    + b2f((ushort)(v2 & 0xffff)) + b2f((ushort)(v3 & 0xffff));
                ay += b2f((ushort)(v0 >> 16)) + b2f((ushort)(v1 >> 16))
                    + b2f((ushort)(v2 >> 16)) + b2f((ushort)(v3 >> 16));
            }
            for (; k < end; ++k) {
                const uint v = *(const uint*)&h[((size_t)esrc[k] << 7) + (lane << 1)];
                ax += b2f((ushort)(v & 0xffff));
                ay += b2f((ushort)(v >> 16));
            }
            *(uint*)&agg[((size_t)node << 7) + (lane << 1)] = pack2(ax, ay);
        }
    }
}

// head: out[q] = z[a].topdot + z[b].botdot + lpb  (z = {za0,za1,zb0,zb1})
__launch_bounds__(256)
__global__ void head_kernel(const float4* __restrict__ z, const int* __restrict__ eli,
                            const float* __restrict__ lpb, float* __restrict__ out, int Q)
{
    const int q = blockIdx.x * 256 + threadIdx.x;
    if (q >= Q) return;
    const int a = eli[q];
    const int b = eli[Q + q];
    const float4 za = z[a];
    const float4 zb = z[b];
    float2 o = make_float2(za.x + zb.z + lpb[0], za.y + zb.w + lpb[1]);
    *(float2*)&out[(size_t)q * 2] = o;
}

extern "C" void kernel_launch(void* const* d_in, const int* in_sizes, int n_in,
                              void* d_out, int out_size, void* d_ws, size_t ws_size,
                              hipStream_t stream)
{
    const float* nf   = (const float*)d_in[0];
    const int*   ei   = (const int*)d_in[1];
    const float* ef   = (const float*)d_in[2];
    const int*   eli  = (const int*)d_in[3];
    const float* c1pW = (const float*)d_in[4];
    const float* c1pb = (const float*)d_in[5];
    const float* c1mW = (const float*)d_in[6];
    const float* c1mb = (const float*)d_in[7];
    const float* c2pW = (const float*)d_in[8];
    const float* c2pb = (const float*)d_in[9];
    const float* c2mW = (const float*)d_in[10];
    const float* c2mb = (const float*)d_in[11];
    const float* lpW  = (const float*)d_in[12];
    const float* lpb  = (const float*)d_in[13];
    float* out = (float*)d_out;

    const int N = in_sizes[0] / 128;
    const int E = in_sizes[1] / 2;
    const int Q = in_sizes[3] / 2;

    // ---- workspace layout ----
    float* DEG = (float*)d_ws;                 // N
    float* z   = DEG + N;                      // N*4 fp32 (head projections)
    int* counts    = (int*)(z + (size_t)N * 4);// N
    int* rowstart  = counts + N;               // N+1
    int* cursor    = rowstart + N + 1;         // N
    int* blocksums = cursor + N;               // 1024 pad
    int* esrc      = blocksums + 1024;         // E
    int* eeid      = esrc + E;                 // E
    uintptr_t up = (uintptr_t)(eeid + E);
    up = (up + 15) & ~(uintptr_t)15;
    ushort* h_bf   = (ushort*)up;              // N*128
    ushort* agg_bf = h_bf   + (size_t)N * 128; // N*128
    ushort* x1_bf  = agg_bf + (size_t)N * 128; // N*128
    ushort* ef_bf  = x1_bf  + (size_t)N * 128; // N*16
    ushort* wtp1   = ef_bf  + (size_t)N * 16;  // 128*128
    ushort* wtm1   = wtp1 + 128 * 128;         // 128*320
    ushort* wtp2   = wtm1 + 128 * 320;         // 128*128
    ushort* wtm2   = wtp2 + 128 * 128;         // 128*320

    const int gemmGrid = (N + 127) / 128;
    const int eGrid    = (E + 255) / 256;
    const int nGrid    = (N + 255) / 256;
    const int gGrid    = (N + 3) / 4;
    const int headGrid = (Q + 255) / 256;

    // ---- prep + CSR build ----
    prep<<<nGrid, 256, 0, stream>>>(c1pW, c2pW, c1mW, c2mW, wtp1, wtp2, wtm1, wtm2,
                                    counts, N);
    hist_kernel<<<eGrid, 256, 0, stream>>>(ei, counts, E);
    scan_phase1<<<nGrid, 256, 0, stream>>>(counts, rowstart, blocksums, N);
    scan_phase23<<<nGrid, 256, 0, stream>>>(counts, blocksums, rowstart, cursor, DEG, N, E);
    build_elist<<<eGrid, 256, 0, stream>>>(ei, cursor, esrc, eeid, E);

    // ---- conv1 ----
    gemm_mfma<<<gemmGrid, 256, 0, stream>>>(nullptr, nullptr, nullptr, nf, DEG, wtp1,
                                            c1pb, h_bf, nullptr, nullptr, N, 128,
                                            F_RELU | F_OUTB | F_IN32);
    gather<<<gGrid, 256, 0, stream>>>(esrc, eeid, rowstart, h_bf, agg_bf, ef, ef_bf, N, 1);
    gemm_mfma<<<gemmGrid, 256, 0, stream>>>(h_bf, agg_bf, ef_bf, nullptr, DEG, wtm1,
                                            c1mb, x1_bf, nullptr, nullptr, N, 320,
                                            F_MSG | F_RELU | F_DEGBIAS | F_OUTB);

    // ---- conv2 ----
    gemm_mfma<<<gemmGrid, 256, 0, stream>>>(x1_bf, nullptr, nullptr, nullptr, DEG, wtp2,
                                            c2pb, h_bf, nullptr, nullptr, N, 128,
                                            F_RELU | F_OUTB);
    gather<<<gGrid, 256, 0, stream>>>(esrc, eeid, rowstart, h_bf, agg_bf, nullptr, nullptr, N, 0);
    gemm_mfma<<<gemmGrid, 256, 0, stream>>>(h_bf, agg_bf, ef_bf, nullptr, DEG, wtm2,
                                            c2mb, nullptr, lpW, z, N, 320,
                                            F_MSG | F_DEGBIAS | F_HEAD);

    // ---- head ----
    head_kernel<<<headGrid, 256, 0, stream>>>((const float4*)z, eli, lpb, out, Q);
}